// Round 6
// baseline (2715.814 us; speedup 1.0000x reference)
//
#include <hip/hip_runtime.h>
#include <cstdint>
#include <cstddef>

// Problem constants (match reference setup_inputs)
#define NPTS 16384   // N
#define NSAMP 1024   // SAMPLES
#define KNBR 32      // MAX_NEIGHBORS
#define NCH 128      // C
#define FPS_TPB 512  // FPS block size (8 waves)
#define NCELL 256    // 8 x 8 x 4 spatial grid

// ---------------------------------------------------------------------------
// Kernel 1: farthest point sampling with spatial cell pruning (QuickFPS-style).
// One block per batch (4 blocks).
//
// ROUND-5 LESSON: the sentinel s_cellkey=~0ull made cellmax=NaN; ordered
// compare (bnd*margin < NaN) == false -> every cell inactive forever -> all
// centroids = point 0 (absmax 0.97, exactly the predicted failure signature).
// Init must use a FINITE cellmax (1e10f bits) so iteration 1 activates all
// cells and overwrites every key with real values.
//
// Exactness contract (absmax must stay 0):
//  - processed points: d = (dx*dx+dy*dy)+dz*dz, contract(off), md=fminf(md,d)
//    — identical op sequence to the reference.
//  - binning is EXACT: x*8.0f / z*4.0f are power-of-2 scalings (exact), so
//    (int) truncation puts each point exactly in [ix/8,(ix+1)/8) etc.; bbox
//    corners ix*0.125f / iz*0.25f are exact f32.
//  - skipped cells: skip only if fl(bnd*0.99999f) >= cellmax (= max md in
//    cell, from key high bits). fl_d >= real_d(1-5e) >= real_bnd(1-5e) >=
//    fl_bnd(1-10e) and fl(fl_bnd*0.99999) <= fl_bnd(1-1e-5+2e), 1e-5 >> 15e
//    (e=2^-24) -> skip implies fminf is a no-op for every cell point -> md
//    and the cell's key are bit-identical unchanged.
//  - argmax via exact packed keys (mdbits<<32)|~origidx, max-reduce (md>=0
//    so f32 bits are u32-monotone; ~idx = smallest-index tie-break, matching
//    numpy argmax first-occurrence). Scatter order nondeterminism is
//    harmless: keys carry ORIGINAL indices, updates are order-independent.
//  - empty cells: processed once in iter 1 -> key=0 -> cellmax=0 -> never
//    active again; key=0 can never win (any real point's key has md bits > 0
//    or a valid ~idx dominating only among md==0 ties, and max md > 0 always).
// ---------------------------------------------------------------------------
__global__ __launch_bounds__(FPS_TPB) void fps_kernel(
    const float* __restrict__ xyz, float* __restrict__ centroids,
    float4* __restrict__ wpt, int* __restrict__ wid) {
#pragma clang fp contract(off)
  const int b = blockIdx.x;
  const int t = threadIdx.x;
  const int wave = t >> 6;
  const int lane = t & 63;
  const float* px = xyz + (size_t)b * NPTS * 3;
  float4* wp = wpt + (size_t)b * NPTS;  // permuted (x,y,z,md) per point
  int* wi = wid + (size_t)b * NPTS;     // original index per permuted slot

  __shared__ int s_cnt[NCELL];    // cell sizes
  __shared__ int s_start[NCELL];  // CSR starts
  __shared__ int s_cur[NCELL];    // scatter cursors
  __shared__ int s_ps[NCELL];     // prefix-sum scratch
  __shared__ unsigned long long s_cellkey[NCELL];  // (maxmd bits<<32)|~argidx
  __shared__ int s_actlist[NCELL];
  __shared__ int s_nact;
  __shared__ unsigned long long s_wred[8];

  // ---- setup: histogram -> prefix sum -> scatter (one-time, ~10 us) ----
  if (t < NCELL) {
    s_cnt[t] = 0;
    // FINITE sentinel (NOT ~0ull = NaN cellmax!): guarantees iter-1 activity.
    s_cellkey[t] = ((unsigned long long)__float_as_uint(1e10f) << 32);
  }
  if (t == 0) s_nact = 0;
  __syncthreads();

  for (int j = 0; j < NPTS / FPS_TPB; ++j) {
    const int p = j * FPS_TPB + t;
    const float x = px[p * 3 + 0];
    const float y = px[p * 3 + 1];
    const float z = px[p * 3 + 2];
    const int cx8 = min(7, (int)(x * 8.0f));  // clamp: x==1.0 only (excluded)
    const int cy8 = min(7, (int)(y * 8.0f));
    const int cz4 = min(3, (int)(z * 4.0f));
    atomicAdd(&s_cnt[cx8 * 32 + cy8 * 4 + cz4], 1);
  }
  __syncthreads();

  // inclusive Hillis-Steele scan of s_cnt into s_ps
  if (t < NCELL) s_ps[t] = s_cnt[t];
  __syncthreads();
  for (int off = 1; off < NCELL; off <<= 1) {
    int v = 0;
    if (t < NCELL) { v = s_ps[t]; if (t >= off) v += s_ps[t - off]; }
    __syncthreads();
    if (t < NCELL) s_ps[t] = v;
    __syncthreads();
  }
  if (t < NCELL) {
    const int st = (t == 0) ? 0 : s_ps[t - 1];
    s_start[t] = st;
    s_cur[t] = st;
  }
  __syncthreads();

  for (int j = 0; j < NPTS / FPS_TPB; ++j) {
    const int p = j * FPS_TPB + t;
    const float x = px[p * 3 + 0];
    const float y = px[p * 3 + 1];
    const float z = px[p * 3 + 2];
    const int cx8 = min(7, (int)(x * 8.0f));
    const int cy8 = min(7, (int)(y * 8.0f));
    const int cz4 = min(3, (int)(z * 4.0f));
    const int pos = atomicAdd(&s_cur[cx8 * 32 + cy8 * 4 + cz4], 1);
    wp[pos] = make_float4(x, y, z, 1e10f);  // md init here
    wi[pos] = p;
  }
  __syncthreads();  // global scatter visible block-wide past the barrier

  // ---- first centroid = point 0 ----
  float* co = centroids + (size_t)b * NSAMP * 3;
  float lx = px[0], ly = px[1], lz = px[2];  // uniform broadcast loads
  if (t == 0) { co[0] = lx; co[1] = ly; co[2] = lz; }

  // ---- main loop ----
  for (int s = 1; s < NSAMP; ++s) {
    // phase 1: bound test per cell (threads 0..255), compact active list.
    if (t < NCELL) {
      const float lox = (float)(t >> 5) * 0.125f;
      const float loy = (float)((t >> 2) & 7) * 0.125f;
      const float loz = (float)(t & 3) * 0.25f;
      const float tx = fmaxf(fmaxf(lox - lx, lx - (lox + 0.125f)), 0.0f);
      const float ty = fmaxf(fmaxf(loy - ly, ly - (loy + 0.125f)), 0.0f);
      const float tz = fmaxf(fmaxf(loz - lz, lz - (loz + 0.25f)), 0.0f);
      const float bnd = (tx * tx + ty * ty) + tz * tz;
      const float cellmax = __uint_as_float((unsigned)(s_cellkey[t] >> 32));
      if (bnd * 0.99999f < cellmax) {  // conservative: borderline -> active
        const int pos = atomicAdd(&s_nact, 1);
        s_actlist[pos] = t;
      }
    }
    __syncthreads();  // B1

    // phase 2: update active cells (one wave per cell, strided)
    const int nact = s_nact;
    for (int a = wave; a < nact; a += FPS_TPB / 64) {
      const int c = s_actlist[a];
      const int st = s_start[c];
      const int en = st + s_cnt[c];
      unsigned long long key = 0;  // neutral (md bits 0, idx huge)
      for (int p0 = st; p0 < en; p0 += 64) {
        const int p = p0 + lane;
        unsigned long long k = 0;
        if (p < en) {
          const float4 q = wp[p];
          const float dx = q.x - lx;
          const float dy = q.y - ly;
          const float dz = q.z - lz;
          const float d = (dx * dx + dy * dy) + dz * dz;  // no FMA
          const float mm = fminf(q.w, d);
          if (mm < q.w) ((float*)(wp + p))[3] = mm;  // store only on change
          k = ((unsigned long long)__float_as_uint(mm) << 32) |
              (unsigned int)(~(unsigned int)wi[p]);
        }
        if (k > key) key = k;  // per-lane max across chunks
      }
      // one butterfly per cell
#pragma unroll
      for (int o = 1; o < 64; o <<= 1) {
        const unsigned long long ok = __shfl_xor(key, o);
        if (ok > key) key = ok;
      }
      if (lane == 0) s_cellkey[c] = key;
    }
    __syncthreads();  // B2

    // phase 3: argmax over the 256 exact cell keys (waves 0-3 hold them)
    unsigned long long k3 = (t < NCELL) ? s_cellkey[t] : 0ull;
#pragma unroll
    for (int o = 1; o < 64; o <<= 1) {
      const unsigned long long ok = __shfl_xor(k3, o);
      if (ok > k3) k3 = ok;
    }
    if (lane == 0 && t < NCELL) s_wred[wave] = k3;
    if (t == 0) s_nact = 0;  // reset here: all phase-1 atomics were pre-B1
    __syncthreads();  // B3

    unsigned long long best = s_wred[0];
#pragma unroll
    for (int w = 1; w < 4; ++w) {
      const unsigned long long k2 = s_wred[w];
      if (k2 > best) best = k2;
    }
    const unsigned int widx = ~(unsigned int)best;

    // winner coords: uniform broadcast load from ORIGINAL array (L1-hot)
    lx = px[widx * 3 + 0];
    ly = px[widx * 3 + 1];
    lz = px[widx * 3 + 2];
    if (t == 0) {
      co[s * 3 + 0] = lx;
      co[s * 3 + 1] = ly;
      co[s * 3 + 2] = lz;
    }
  }
}

// ---------------------------------------------------------------------------
// Kernel 2: ball query (first K in-radius by index order, pad with first hit)
// + gather. One wave per (b,s) centroid; 4 waves per 256-thread block.
// Ordered chunk scan with ballot + prefix popcount, early exit at K found.
// (Validated bit-exact in rounds 1-4; unchanged.)
// ---------------------------------------------------------------------------
__global__ __launch_bounds__(256) void group_kernel(
    const float* __restrict__ xyz, const float* __restrict__ feat,
    const float* __restrict__ centroids,
    float* __restrict__ gxyz, float* __restrict__ gfeat) {
#pragma clang fp contract(off)
  const int wave = threadIdx.x >> 6;
  const int lane = threadIdx.x & 63;
  const int gw = blockIdx.x * 4 + wave;  // == b * NSAMP + s
  const int b = gw >> 10;

  const float* px = xyz + (size_t)b * NPTS * 3;
  const float* pc = centroids + (size_t)gw * 3;
  const float cx = pc[0], cy = pc[1], cz = pc[2];
  // float32(0.04): numpy compares f32 sqd against python-double 0.04 demoted
  // to f32. NOT 0.2f*0.2f (that's a different float, 1 ulp larger).
  const float rr = 0.04f;

  __shared__ int sh_idx[4][KNBR];
  __shared__ float sh_gx[4][KNBR * 3];

  int cnt = 0;
  for (int n0 = 0; n0 < NPTS && cnt < KNBR; n0 += 64) {
    const int p = n0 + lane;
    const float xx = px[p * 3 + 0];
    const float yy = px[p * 3 + 1];
    const float zz = px[p * 3 + 2];
    const float dx = xx - cx;
    const float dy = yy - cy;
    const float dz = zz - cz;
    const float d = (dx * dx + dy * dy) + dz * dz;  // contract(off): no FMA
    const bool in = d <= rr;
    const unsigned long long mask = __ballot(in);
    const int pos = cnt + (int)__popcll(mask & ((1ull << lane) - 1ull));
    if (in && pos < KNBR) {
      sh_idx[wave][pos] = p;
      sh_gx[wave][pos * 3 + 0] = dx;
      sh_gx[wave][pos * 3 + 1] = dy;
      sh_gx[wave][pos * 3 + 2] = dz;
    }
    cnt += (int)__popcll(mask);
  }
  // Safety: cannot happen (centroid is itself in-ball), but avoid garbage
  // indices if it somehow does.
  if (cnt == 0 && lane == 0) {
    sh_idx[wave][0] = 0;
    sh_gx[wave][0] = px[0] - cx;
    sh_gx[wave][1] = px[1] - cy;
    sh_gx[wave][2] = px[2] - cz;
  }
  const int nf0 = (cnt < 1) ? 1 : cnt;
  const int nf = (nf0 < KNBR) ? nf0 : KNBR;
  __syncthreads();
  // pad slots [nf, K) with the first hit (matches reference padding)
  if (lane < KNBR && lane >= nf) {
    sh_idx[wave][lane] = sh_idx[wave][0];
    sh_gx[wave][lane * 3 + 0] = sh_gx[wave][0];
    sh_gx[wave][lane * 3 + 1] = sh_gx[wave][1];
    sh_gx[wave][lane * 3 + 2] = sh_gx[wave][2];
  }
  __syncthreads();

  // write grouped_xyz: 96 floats per centroid
  float* ox = gxyz + (size_t)gw * KNBR * 3;
  const float* shf = sh_gx[wave];
  for (int j = lane; j < KNBR * 3; j += 64) ox[j] = shf[j];

  // gather features: K rows of 128 floats, float2 per lane (512 B/row)
  float* og = gfeat + (size_t)gw * KNBR * NCH;
  const float* pf = feat + (size_t)b * NPTS * NCH;
#pragma unroll 4
  for (int k = 0; k < KNBR; ++k) {
    const int row = sh_idx[wave][k];
    const float2 v = ((const float2*)(pf + (size_t)row * NCH))[lane];
    ((float2*)(og + (size_t)k * NCH))[lane] = v;
  }
}

extern "C" void kernel_launch(void* const* d_in, const int* in_sizes, int n_in,
                              void* d_out, int out_size, void* d_ws, size_t ws_size,
                              hipStream_t stream) {
  const float* xyz = (const float*)d_in[0];
  const float* feat = (const float*)d_in[1];
  float* out = (float*)d_out;
  const int B = in_sizes[0] / (NPTS * 3);

  float* centroids = out;                                   // [B,S,3]
  float* gxyz = centroids + (size_t)B * NSAMP * 3;          // [B,S,K,3]
  float* gfeat = gxyz + (size_t)B * NSAMP * KNBR * 3;       // [B,S,K,C]

  // scratch: per-batch permuted (x,y,z,md) float4 + original-index array.
  // B=4 -> 1.25 MB, well under any sane ws_size.
  float4* wpt = (float4*)d_ws;
  int* wid = (int*)(wpt + (size_t)B * NPTS);

  fps_kernel<<<B, FPS_TPB, 0, stream>>>(xyz, centroids, wpt, wid);
  group_kernel<<<(B * NSAMP) / 4, 256, 0, stream>>>(xyz, feat, centroids, gxyz, gfeat);
}

// Round 7
// 2253.706 us; speedup vs baseline: 1.2050x; 1.2050x over previous
//
#include <hip/hip_runtime.h>
#include <cstdint>
#include <cstddef>

// Problem constants (match reference setup_inputs)
#define NPTS 16384   // N
#define NSAMP 1024   // SAMPLES
#define KNBR 32      // MAX_NEIGHBORS
#define NCH 128      // C
#define FPS_TPB 1024 // FPS block size (16 waves)
#define NWAVES (FPS_TPB / 64)
#define NCELL 256    // 8 x 8 x 4 spatial grid

typedef unsigned long long u64;

// ---------------------------------------------------------------------------
// Kernel 1: farthest point sampling with spatial cell pruning. One block per
// batch (4 blocks).
//
// ROUND-6 LESSON: pruning was correct but latency-bound (~6100 cyc/iter,
// VALUBusy 0.27%, VGPR=20): phase 2's per-cell dependent chain ran fully
// serialized, ~4-5 cells/wave on 8 waves, plus same-address LDS atomics and
// a dependent global winner-coords load. This round: 16 waves, manual 2-deep
// prefetch pipeline in phase 2, winner coords kept per-cell in LDS (phase 3
// carries the winning CELL id), packed cell meta.
//
// Exactness contract (absmax must stay 0):
//  - processed points: d = (dx*dx+dy*dy)+dz*dz, contract(off), md=fminf(md,d)
//    — identical op sequence to the reference; coords flow bit-exact
//    px -> wp(float4) -> registers -> s_cx/cy/cz.
//  - binning exact (power-of-2 scalings); bbox corners exact f32.
//  - skip only if fl(bnd*0.99999f) >= cellmax: fl_d >= real_d(1-5e) >=
//    real_bnd(1-5e) >= fl_bnd(1-10e); fl(fl_bnd*0.99999) <= fl_bnd(1-1e-5+2e);
//    1e-5 >> 15e (e=2^-24) -> skip implies fminf no-op for every cell point
//    -> cell state bit-identical unchanged.
//  - argmax via exact packed keys (mdbits<<32)|~origidx (md>=0 -> u32-monotone;
//    ~idx = smallest-index tie-break = numpy argmax). Keys unique per point,
//    so ballot(pre==final) identifies the true winner lane.
//  - winner's cell always reactivates (bnd=0 < its cmax>0), so the picked
//    point's md is zeroed next iteration (no re-pick).
//  - empty cells: processed once in iter 1 (cmax sentinel 1e10 FINITE — the
//    round-5 NaN lesson) -> key=0, cmax=0 -> dead; key 0 never wins.
// ---------------------------------------------------------------------------
__global__ __launch_bounds__(FPS_TPB)
__attribute__((amdgpu_waves_per_eu(4, 4)))  // 1 block/CU: keep pipeline regs
void fps_kernel(const float* __restrict__ xyz, float* __restrict__ centroids,
                float4* __restrict__ wpt, int* __restrict__ wid) {
#pragma clang fp contract(off)
  const int b = blockIdx.x;
  const int t = threadIdx.x;
  const int wave = t >> 6;
  const int lane = t & 63;
  const float* px = xyz + (size_t)b * NPTS * 3;
  float4* wp = wpt + (size_t)b * NPTS;  // permuted (x,y,z,md) per point
  int* wi = wid + (size_t)b * NPTS;     // original index per permuted slot

  __shared__ int s_cnt[NCELL];
  __shared__ int s_ps[NCELL];
  __shared__ int s_cur[NCELL];
  __shared__ unsigned s_meta[NCELL];  // start<<16 | cnt
  __shared__ u64 s_cellkey[NCELL];    // exact (maxmd bits<<32)|~argidx
  __shared__ float s_cmax[NCELL];     // f32 view of key high bits
  __shared__ float s_cx[NCELL], s_cy[NCELL], s_cz[NCELL];  // cell winner xyz
  __shared__ int s_actlist[NCELL];
  __shared__ int s_nact;
  __shared__ u64 s_p3key[4];
  __shared__ int s_p3cell[4];

  // ---- setup: histogram -> prefix sum -> scatter (one-time) ----
  if (t < NCELL) {
    s_cnt[t] = 0;
    s_cmax[t] = 1e10f;  // FINITE sentinel: iter 1 activates all cells
    s_cellkey[t] = ((u64)__float_as_uint(1e10f) << 32);
  }
  if (t == 0) s_nact = 0;
  __syncthreads();

  for (int j = 0; j < NPTS / FPS_TPB; ++j) {
    const int p = j * FPS_TPB + t;
    const float x = px[p * 3 + 0];
    const float y = px[p * 3 + 1];
    const float z = px[p * 3 + 2];
    const int cx8 = min(7, (int)(x * 8.0f));
    const int cy8 = min(7, (int)(y * 8.0f));
    const int cz4 = min(3, (int)(z * 4.0f));
    atomicAdd(&s_cnt[cx8 * 32 + cy8 * 4 + cz4], 1);
  }
  __syncthreads();

  if (t < NCELL) s_ps[t] = s_cnt[t];
  __syncthreads();
  for (int off = 1; off < NCELL; off <<= 1) {
    int v = 0;
    if (t < NCELL) { v = s_ps[t]; if (t >= off) v += s_ps[t - off]; }
    __syncthreads();
    if (t < NCELL) s_ps[t] = v;
    __syncthreads();
  }
  if (t < NCELL) {
    const int st = (t == 0) ? 0 : s_ps[t - 1];
    s_cur[t] = st;
    s_meta[t] = ((unsigned)st << 16) | (unsigned)s_cnt[t];
  }
  __syncthreads();

  for (int j = 0; j < NPTS / FPS_TPB; ++j) {
    const int p = j * FPS_TPB + t;
    const float x = px[p * 3 + 0];
    const float y = px[p * 3 + 1];
    const float z = px[p * 3 + 2];
    const int cx8 = min(7, (int)(x * 8.0f));
    const int cy8 = min(7, (int)(y * 8.0f));
    const int cz4 = min(3, (int)(z * 4.0f));
    const int pos = atomicAdd(&s_cur[cx8 * 32 + cy8 * 4 + cz4], 1);
    wp[pos] = make_float4(x, y, z, 1e10f);
    wi[pos] = p;
  }
  __syncthreads();

  // ---- first centroid = point 0 ----
  float* co = centroids + (size_t)b * NSAMP * 3;
  float lx = px[0], ly = px[1], lz = px[2];
  if (t == 0) { co[0] = lx; co[1] = ly; co[2] = lz; }

  // ---- main loop: 3 barriers per iteration ----
  for (int s = 1; s < NSAMP; ++s) {
    // phase 1: bound test per cell (threads 0..255), compact active list
    if (t < NCELL) {
      const float lox = (float)(t >> 5) * 0.125f;
      const float loy = (float)((t >> 2) & 7) * 0.125f;
      const float loz = (float)(t & 3) * 0.25f;
      const float tx = fmaxf(fmaxf(lox - lx, lx - (lox + 0.125f)), 0.0f);
      const float ty = fmaxf(fmaxf(loy - ly, ly - (loy + 0.125f)), 0.0f);
      const float tz = fmaxf(fmaxf(loz - lz, lz - (loz + 0.25f)), 0.0f);
      const float bnd = (tx * tx + ty * ty) + tz * tz;
      if (bnd * 0.99999f < s_cmax[t]) {  // conservative: borderline -> active
        const int pos = atomicAdd(&s_nact, 1);
        s_actlist[pos] = t;
      }
    }
    __syncthreads();  // B1: actlist ready

    // phase 2: update active cells, one wave per cell, 2-deep prefetch
    const int nact = s_nact;
    int slot = wave;
    int c = -1, cst = 0, ccnt = 0, id0 = 0;
    float4 q = make_float4(0.f, 0.f, 0.f, 0.f);
    if (slot < nact) {
      c = s_actlist[slot];
      const unsigned m = s_meta[c];
      cst = (int)(m >> 16);
      ccnt = (int)(m & 0xFFFF);
      if (lane < ccnt) { q = wp[cst + lane]; id0 = wi[cst + lane]; }
    }
    while (slot < nact) {
      // prefetch NEXT cell (control + first chunk) before current compute
      const int nslot = slot + NWAVES;
      int nc = -1, nst = 0, ncnt = 0, nid = 0;
      float4 nq = make_float4(0.f, 0.f, 0.f, 0.f);
      if (nslot < nact) {
        nc = s_actlist[nslot];
        const unsigned m = s_meta[nc];
        nst = (int)(m >> 16);
        ncnt = (int)(m & 0xFFFF);
        if (lane < ncnt) { nq = wp[nst + lane]; nid = wi[nst + lane]; }
      }
      // prefetch current cell's second chunk (cnt in (64,128] ~ half of cells)
      float4 q1 = make_float4(0.f, 0.f, 0.f, 0.f);
      int id1 = 0;
      const bool has2 = (64 + lane < ccnt);
      if (has2) { q1 = wp[cst + 64 + lane]; id1 = wi[cst + 64 + lane]; }

      u64 key = 0;
      float bx = 0.f, by = 0.f, bz = 0.f;
      if (lane < ccnt) {
        const float dx = q.x - lx, dy = q.y - ly, dz = q.z - lz;
        const float d = (dx * dx + dy * dy) + dz * dz;  // no FMA
        const float mm = fminf(q.w, d);
        if (mm < q.w) ((float*)(wp + cst + lane))[3] = mm;
        key = ((u64)__float_as_uint(mm) << 32) | (unsigned)(~(unsigned)id0);
        bx = q.x; by = q.y; bz = q.z;
      }
      if (has2) {
        const float dx = q1.x - lx, dy = q1.y - ly, dz = q1.z - lz;
        const float d = (dx * dx + dy * dy) + dz * dz;
        const float mm = fminf(q1.w, d);
        if (mm < q1.w) ((float*)(wp + cst + 64 + lane))[3] = mm;
        const u64 k = ((u64)__float_as_uint(mm) << 32) | (unsigned)(~(unsigned)id1);
        if (k > key) { key = k; bx = q1.x; by = q1.y; bz = q1.z; }
      }
      for (int p0 = 128; p0 < ccnt; p0 += 64) {  // ultra-rare residual
        if (p0 + lane < ccnt) {
          const int p = cst + p0 + lane;
          const float4 qq = wp[p];
          const float dx = qq.x - lx, dy = qq.y - ly, dz = qq.z - lz;
          const float d = (dx * dx + dy * dy) + dz * dz;
          const float mm = fminf(qq.w, d);
          if (mm < qq.w) ((float*)(wp + p))[3] = mm;
          const u64 k = ((u64)__float_as_uint(mm) << 32) |
                        (unsigned)(~(unsigned)wi[p]);
          if (k > key) { key = k; bx = qq.x; by = qq.y; bz = qq.z; }
        }
      }
      const u64 pre = key;
#pragma unroll
      for (int o = 1; o < 64; o <<= 1) {
        const u64 ok = __shfl_xor(key, o);
        if (ok > key) key = ok;
      }
      // winner lane (key unique per point; empty cell -> all pre==0 -> lane 0)
      const u64 mb = __ballot(pre == key);
      if (lane == (int)__builtin_ctzll(mb)) {
        s_cellkey[c] = key;
        s_cmax[c] = __uint_as_float((unsigned)(key >> 32));
        s_cx[c] = bx; s_cy[c] = by; s_cz[c] = bz;
      }
      slot = nslot; c = nc; cst = nst; ccnt = ncnt; q = nq; id0 = nid;
    }
    __syncthreads();  // B2: all cell keys/coords current

    // phase 3: argmax over 256 exact cell keys (waves 0-3), carry cell id
    if (t < NCELL) {
      const u64 pre3 = s_cellkey[t];
      u64 fin = pre3;
#pragma unroll
      for (int o = 1; o < 64; o <<= 1) {
        const u64 ok = __shfl_xor(fin, o);
        if (ok > fin) fin = ok;
      }
      const u64 mb3 = __ballot(pre3 == fin);
      if (lane == (int)__builtin_ctzll(mb3)) {
        s_p3key[wave] = fin;
        s_p3cell[wave] = t;
      }
    }
    if (t == 0) s_nact = 0;  // safe: phase-2 reads done pre-B2
    __syncthreads();  // B3: partials ready

    // final: every thread picks the winner and reads its coords from LDS
    u64 bk = s_p3key[0];
    int bc = s_p3cell[0];
#pragma unroll
    for (int w = 1; w < 4; ++w) {
      const u64 k2 = s_p3key[w];
      if (k2 > bk) { bk = k2; bc = s_p3cell[w]; }
    }
    lx = s_cx[bc]; ly = s_cy[bc]; lz = s_cz[bc];
    if (t == 0) {
      co[s * 3 + 0] = lx;
      co[s * 3 + 1] = ly;
      co[s * 3 + 2] = lz;
    }
    // next phase-1 reads s_cmax (written pre-B2) and writes s_actlist after
    // all waves pass B3; s_cx reads complete before any wave passes B1. safe.
  }
}

// ---------------------------------------------------------------------------
// Kernel 2: ball query (first K in-radius by index order, pad with first hit)
// + gather. One wave per (b,s) centroid; 4 waves per 256-thread block.
// (Validated bit-exact in rounds 1-6; unchanged.)
// ---------------------------------------------------------------------------
__global__ __launch_bounds__(256) void group_kernel(
    const float* __restrict__ xyz, const float* __restrict__ feat,
    const float* __restrict__ centroids,
    float* __restrict__ gxyz, float* __restrict__ gfeat) {
#pragma clang fp contract(off)
  const int wave = threadIdx.x >> 6;
  const int lane = threadIdx.x & 63;
  const int gw = blockIdx.x * 4 + wave;  // == b * NSAMP + s
  const int b = gw >> 10;

  const float* px = xyz + (size_t)b * NPTS * 3;
  const float* pc = centroids + (size_t)gw * 3;
  const float cx = pc[0], cy = pc[1], cz = pc[2];
  // float32(0.04): numpy compares f32 sqd against python-double 0.04 demoted
  // to f32. NOT 0.2f*0.2f (that's a different float, 1 ulp larger).
  const float rr = 0.04f;

  __shared__ int sh_idx[4][KNBR];
  __shared__ float sh_gx[4][KNBR * 3];

  int cnt = 0;
  for (int n0 = 0; n0 < NPTS && cnt < KNBR; n0 += 64) {
    const int p = n0 + lane;
    const float xx = px[p * 3 + 0];
    const float yy = px[p * 3 + 1];
    const float zz = px[p * 3 + 2];
    const float dx = xx - cx;
    const float dy = yy - cy;
    const float dz = zz - cz;
    const float d = (dx * dx + dy * dy) + dz * dz;  // contract(off): no FMA
    const bool in = d <= rr;
    const unsigned long long mask = __ballot(in);
    const int pos = cnt + (int)__popcll(mask & ((1ull << lane) - 1ull));
    if (in && pos < KNBR) {
      sh_idx[wave][pos] = p;
      sh_gx[wave][pos * 3 + 0] = dx;
      sh_gx[wave][pos * 3 + 1] = dy;
      sh_gx[wave][pos * 3 + 2] = dz;
    }
    cnt += (int)__popcll(mask);
  }
  // Safety: cannot happen (centroid is itself in-ball), but avoid garbage
  // indices if it somehow does.
  if (cnt == 0 && lane == 0) {
    sh_idx[wave][0] = 0;
    sh_gx[wave][0] = px[0] - cx;
    sh_gx[wave][1] = px[1] - cy;
    sh_gx[wave][2] = px[2] - cz;
  }
  const int nf0 = (cnt < 1) ? 1 : cnt;
  const int nf = (nf0 < KNBR) ? nf0 : KNBR;
  __syncthreads();
  // pad slots [nf, K) with the first hit (matches reference padding)
  if (lane < KNBR && lane >= nf) {
    sh_idx[wave][lane] = sh_idx[wave][0];
    sh_gx[wave][lane * 3 + 0] = sh_gx[wave][0];
    sh_gx[wave][lane * 3 + 1] = sh_gx[wave][1];
    sh_gx[wave][lane * 3 + 2] = sh_gx[wave][2];
  }
  __syncthreads();

  // write grouped_xyz: 96 floats per centroid
  float* ox = gxyz + (size_t)gw * KNBR * 3;
  const float* shf = sh_gx[wave];
  for (int j = lane; j < KNBR * 3; j += 64) ox[j] = shf[j];

  // gather features: K rows of 128 floats, float2 per lane (512 B/row)
  float* og = gfeat + (size_t)gw * KNBR * NCH;
  const float* pf = feat + (size_t)b * NPTS * NCH;
#pragma unroll 4
  for (int k = 0; k < KNBR; ++k) {
    const int row = sh_idx[wave][k];
    const float2 v = ((const float2*)(pf + (size_t)row * NCH))[lane];
    ((float2*)(og + (size_t)k * NCH))[lane] = v;
  }
}

extern "C" void kernel_launch(void* const* d_in, const int* in_sizes, int n_in,
                              void* d_out, int out_size, void* d_ws, size_t ws_size,
                              hipStream_t stream) {
  const float* xyz = (const float*)d_in[0];
  const float* feat = (const float*)d_in[1];
  float* out = (float*)d_out;
  const int B = in_sizes[0] / (NPTS * 3);

  float* centroids = out;                                   // [B,S,3]
  float* gxyz = centroids + (size_t)B * NSAMP * 3;          // [B,S,K,3]
  float* gfeat = gxyz + (size_t)B * NSAMP * KNBR * 3;       // [B,S,K,C]

  // scratch: per-batch permuted (x,y,z,md) float4 + original-index array
  float4* wpt = (float4*)d_ws;
  int* wid = (int*)(wpt + (size_t)B * NPTS);

  fps_kernel<<<B, FPS_TPB, 0, stream>>>(xyz, centroids, wpt, wid);
  group_kernel<<<(B * NSAMP) / 4, 256, 0, stream>>>(xyz, feat, centroids, gxyz, gfeat);
}